// Round 9
// baseline (259.925 us; speedup 1.0000x reference)
//
#include <hip/hip_runtime.h>
#include <math.h>

#define BB 64
#define SS 512
#define FF 128
#define UU 512
#define SIGDIM (FF + FF*FF)   // 16512
#define K3 16512              // sig GEMM K
#define KK 1152               // KAN GEMM K: 1024 spline + 128 base
#define SIG_KC 86             // K-chunks for fused sig GEMM (86*3*64 = 16512)
#define SIG_STEPS 3

typedef __attribute__((ext_vector_type(8))) __bf16 bf16x8;
typedef __attribute__((ext_vector_type(8))) unsigned short u16x8;
typedef __attribute__((ext_vector_type(4))) float f32x4;

__device__ __forceinline__ unsigned short f2bf(float x) {
    unsigned int u = __float_as_uint(x);
    unsigned int r = u + 0x7FFFu + ((u >> 16) & 1u);   // RNE
    return (unsigned short)(r >> 16);
}

__device__ __forceinline__ float sigmoidf(float x) { return 1.0f / (1.0f + expf(-x)); }

// ---------------------------------------------------------------------------
// K1 (merged prep): z=0 -> Wt bf16 [512 u][1152 k] + h_prev -> comb_b right
// half; z=1..7 -> small-weight transposes.  grid (16,8,8) x 256 -- wide.
// ---------------------------------------------------------------------------
__global__ __launch_bounds__(256) void k_prep(const float* __restrict__ splw,
                                              const float* __restrict__ basew,
                                              const float* __restrict__ h_prev,
                                              const float* __restrict__ w2, const float* __restrict__ w3,
                                              const float* __restrict__ w4, const float* __restrict__ wf,
                                              const float* __restrict__ wi, const float* __restrict__ wc,
                                              const float* __restrict__ wo,
                                              unsigned short* __restrict__ Wt,
                                              unsigned short* __restrict__ comb_b,
                                              unsigned short* __restrict__ W2t,
                                              unsigned short* __restrict__ W3t,
                                              unsigned short* __restrict__ W4t,
                                              unsigned short* __restrict__ Wgt) {
    int z = blockIdx.z;
    int tid = threadIdx.x;
    if (z == 0) {
        int base = (blockIdx.y * 16 + blockIdx.x) * 256 + tid;   // [0, 32768)
        {
            int b = base >> 9, uu = base & 511;
            comb_b[(size_t)b * 1024 + 512 + uu] = f2bf(h_prev[base]);
        }
        for (int idx = base; idx < UU * KK; idx += 128 * 256) {
            int u = idx / KK, c = idx % KK;
            float v = (c < 1024) ? splw[(size_t)u * 1024 + c] : basew[(size_t)(c - 1024) * UU + u];
            Wt[idx] = f2bf(v);
        }
        return;
    }
    int zz = z - 1;
    int Kdim = (zz < 3) ? 512 : 1024;
    int kt = blockIdx.x, ut = blockIdx.y;
    if (kt * 64 >= Kdim) return;
    const float* src;
    unsigned short* dst;
    switch (zz) {
        case 0: src = w2; dst = W2t; break;
        case 1: src = w3; dst = W3t; break;
        case 2: src = w4; dst = W4t; break;
        case 3: src = wf; dst = Wgt; break;
        case 4: src = wi; dst = Wgt + (size_t)512 * 1024; break;
        case 5: src = wc; dst = Wgt + (size_t)1024 * 1024; break;
        default: src = wo; dst = Wgt + (size_t)1536 * 1024; break;
    }
    __shared__ float tile[64][67];
    int k0 = kt * 64, u0 = ut * 64;
#pragma unroll
    for (int p = 0; p < 4; ++p) {
        int e = p * 256 + tid;
        int kk = e >> 4, c4 = (e & 15) * 4;
        const float4 v = *(const float4*)(src + (size_t)(k0 + kk) * UU + u0 + c4);
        tile[kk][c4 + 0] = v.x;
        tile[kk][c4 + 1] = v.y;
        tile[kk][c4 + 2] = v.z;
        tile[kk][c4 + 3] = v.w;
    }
    __syncthreads();
    int kk0 = (tid & 7) * 8;
#pragma unroll
    for (int p = 0; p < 2; ++p) {
        int uu = (tid >> 3) + p * 32;
        u16x8 ov;
#pragma unroll
        for (int j = 0; j < 8; ++j) ov[j] = f2bf(tile[kk0 + j][uu]);
        *(u16x8*)(dst + (size_t)(u0 + uu) * Kdim + k0 + kk0) = ov;
    }
}

// ---------------------------------------------------------------------------
// K2: a/d/w prep, single fp32 LDS tile.
// ---------------------------------------------------------------------------
__global__ __launch_bounds__(256) void k_adprep(const float* __restrict__ inp,
                                                const float* __restrict__ tk,
                                                unsigned short* __restrict__ aT,
                                                unsigned short* __restrict__ dT,
                                                unsigned short* __restrict__ wT) {
    int tt0 = blockIdx.x * 64, f0 = blockIdx.y * 64, b = blockIdx.z;
    __shared__ float wS[65][67];
    __shared__ float w0S[64];
    int tid = threadIdx.x;
    const float* ib = inp + (size_t)b * SS * FF;
    if (tid < 64) w0S[tid] = tk[0] * ib[f0 + tid];
#pragma unroll
    for (int p = 0; p < 5; ++p) {
        int e = p * 256 + tid;
        if (e < 65 * 16) {
            int row = e >> 4, c4 = (e & 15) * 4;
            int t = tt0 + row;
            if (t < SS) {
                float tkt = tk[t];
                const float4 v = *(const float4*)(ib + (size_t)t * FF + f0 + c4);
                wS[row][c4 + 0] = tkt * v.x;
                wS[row][c4 + 1] = tkt * v.y;
                wS[row][c4 + 2] = tkt * v.z;
                wS[row][c4 + 3] = tkt * v.w;
            } else {
                wS[row][c4 + 0] = 0.f;
                wS[row][c4 + 1] = 0.f;
                wS[row][c4 + 2] = 0.f;
                wS[row][c4 + 3] = 0.f;
            }
        }
    }
    __syncthreads();
    int t8 = (tid & 7) * 8;
#pragma unroll
    for (int p = 0; p < 2; ++p) {
        int ff = (tid >> 3) + p * 32;
        float w0 = w0S[ff];
        u16x8 av, dv, wv;
#pragma unroll
        for (int j = 0; j < 8; ++j) {
            int tt = t8 + j;
            float w = wS[tt][ff];
            float wn = wS[tt + 1][ff];
            bool valid = (tt0 + tt) < (SS - 1);
            float a = valid ? 0.5f * (w + wn) - w0 : 0.f;
            float d = valid ? wn - w : 0.f;
            av[j] = f2bf(a);
            dv[j] = f2bf(d);
            wv[j] = f2bf(w);
        }
        size_t o = ((size_t)b * FF + f0 + ff) * SS + tt0 + t8;
        *(u16x8*)(aT + o) = av;
        *(u16x8*)(dT + o) = dv;
        *(u16x8*)(wT + o) = wv;
    }
}

// ---------------------------------------------------------------------------
// K3: quadrant-tiled full-K signature GEMM, LDS-staged, writes sigb bf16
// directly.  grid (4 quadrant, 64 b) x 256.
// ---------------------------------------------------------------------------
__global__ __launch_bounds__(256) void k_sig_quad(const unsigned short* __restrict__ aT,
                                                  const unsigned short* __restrict__ dT,
                                                  const float* __restrict__ inp,
                                                  const float* __restrict__ tk,
                                                  unsigned short* __restrict__ sigb) {
    int q = blockIdx.x, b = blockIdx.y;
    int qr = q & 1, qc = q >> 1;
    __shared__ unsigned short aS[64][72];
    __shared__ unsigned short dS[64][72];
    int tid = threadIdx.x, lane = tid & 63;
    int wv = __builtin_amdgcn_readfirstlane(tid >> 6);
    int rowoff = (wv & 1) * 32, coloff = (wv >> 1) * 32;
    const unsigned short* pabase = aT + ((size_t)b * FF + qr * 64) * SS;
    const unsigned short* pdbase = dT + ((size_t)b * FF + qc * 64) * SS;

    f32x4 acc[2][2];
#pragma unroll
    for (int i = 0; i < 2; ++i)
#pragma unroll
        for (int j = 0; j < 2; ++j) acc[i][j] = (f32x4)(0.f);

    int arow0 = rowoff + (lane & 15);
    int drow0 = coloff + (lane & 15);
    int kq = (lane >> 4) * 8;

    for (int kc = 0; kc < 8; ++kc) {
#pragma unroll
        for (int p = 0; p < 2; ++p) {
            int e = p * 256 + tid;          // 512 = 64 rows x 8 groups of 8 hw
            int row = e >> 3, k8 = (e & 7) * 8;
            *(u16x8*)&aS[row][k8] = *(const u16x8*)(pabase + (size_t)row * SS + kc * 64 + k8);
            *(u16x8*)&dS[row][k8] = *(const u16x8*)(pdbase + (size_t)row * SS + kc * 64 + k8);
        }
        __syncthreads();
#pragma unroll
        for (int ks = 0; ks < 2; ++ks) {
            bf16x8 af0 = *(const bf16x8*)&aS[arow0][ks * 32 + kq];
            bf16x8 af1 = *(const bf16x8*)&aS[arow0 + 16][ks * 32 + kq];
            bf16x8 df0 = *(const bf16x8*)&dS[drow0][ks * 32 + kq];
            bf16x8 df1 = *(const bf16x8*)&dS[drow0 + 16][ks * 32 + kq];
            acc[0][0] = __builtin_amdgcn_mfma_f32_16x16x32_bf16(af0, df0, acc[0][0], 0, 0, 0);
            acc[0][1] = __builtin_amdgcn_mfma_f32_16x16x32_bf16(af0, df1, acc[0][1], 0, 0, 0);
            acc[1][0] = __builtin_amdgcn_mfma_f32_16x16x32_bf16(af1, df0, acc[1][0], 0, 0, 0);
            acc[1][1] = __builtin_amdgcn_mfma_f32_16x16x32_bf16(af1, df1, acc[1][1], 0, 0, 0);
        }
        __syncthreads();
    }

    unsigned short* ob = sigb + (size_t)b * SIGDIM;
    if (q == 0 && tid < FF) {
        float v = tk[SS - 1] * inp[((size_t)b * SS + SS - 1) * FF + tid] - tk[0] * inp[(size_t)b * SS * FF + tid];
        ob[tid] = f2bf(v);
    }
    int quad = lane >> 4, col = lane & 15;
#pragma unroll
    for (int rt = 0; rt < 2; ++rt)
#pragma unroll
        for (int ct = 0; ct < 2; ++ct)
#pragma unroll
            for (int reg = 0; reg < 4; ++reg)
                ob[FF + (qr * 64 + rowoff + rt * 16 + quad * 4 + reg) * FF
                      + qc * 64 + coloff + ct * 16 + col] = f2bf(acc[rt][ct][reg]);
}

// ---------------------------------------------------------------------------
// K4: fused sig GEMM vs untransposed fp32 weights.
// grid (8 nt, 86 kc, 2 mat) x 256 = 1376 blocks (~5.4/CU).
// ---------------------------------------------------------------------------
__global__ __launch_bounds__(256) void k_sig_fused(const unsigned short* __restrict__ sigb,
                                                   const float* __restrict__ w1,
                                                   const float* __restrict__ gsw,
                                                   float* __restrict__ spart) {
    int nt = blockIdx.x, kc = blockIdx.y, mat = blockIdx.z;
    const float* src = mat ? gsw : w1;
    __shared__ float tile[64][67];
    int tid = threadIdx.x, lane = tid & 63;
    int wv = __builtin_amdgcn_readfirstlane(tid >> 6);
    int u0 = nt * 64;
    int n0 = wv * 16;
    int kbase = kc * (SIG_STEPS * 64);

    f32x4 acc[4];
#pragma unroll
    for (int i = 0; i < 4; ++i) acc[i] = (f32x4)(0.f);

    int nn = lane & 15;
    int kq = (lane >> 4) * 8;
    const unsigned short* pab = sigb + (size_t)nn * K3 + kq;

    for (int step = 0; step < SIG_STEPS; ++step) {
        int k0 = kbase + step * 64;
#pragma unroll
        for (int p = 0; p < 4; ++p) {
            int e = p * 256 + tid;
            int kk = e >> 4, c4 = (e & 15) * 4;
            const float4 v = *(const float4*)(src + (size_t)(k0 + kk) * UU + u0 + c4);
            tile[kk][c4 + 0] = v.x;
            tile[kk][c4 + 1] = v.y;
            tile[kk][c4 + 2] = v.z;
            tile[kk][c4 + 3] = v.w;
        }
        __syncthreads();
#pragma unroll
        for (int s = 0; s < 2; ++s) {
            u16x8 ub;
            int kb = s * 32 + kq;
#pragma unroll
            for (int j = 0; j < 8; ++j) ub[j] = f2bf(tile[kb + j][n0 + nn]);
            bf16x8 bfrag = __builtin_bit_cast(bf16x8, ub);
#pragma unroll
            for (int rt = 0; rt < 4; ++rt) {
                bf16x8 afrag = *(const bf16x8*)(pab + (size_t)(rt * 16) * K3 + k0 + s * 32);
                acc[rt] = __builtin_amdgcn_mfma_f32_16x16x32_bf16(afrag, bfrag, acc[rt], 0, 0, 0);
            }
        }
        __syncthreads();
    }

    int col = lane & 15, quad = lane >> 4;
    float* P = spart + ((size_t)(mat * SIG_KC + kc) * 64) * UU;
#pragma unroll
    for (int rt = 0; rt < 4; ++rt)
#pragma unroll
        for (int reg = 0; reg < 4; ++reg)
            P[(size_t)(rt * 16 + quad * 4 + reg) * UU + u0 + n0 + col] = acc[rt][reg];
}

// ---------------------------------------------------------------------------
// K5: reduce 86 K-chunk partials.
// ---------------------------------------------------------------------------
__global__ __launch_bounds__(256) void k_sig_red2(const float* __restrict__ spart,
                                                  const float* __restrict__ b1,
                                                  unsigned short* __restrict__ h1b,
                                                  float* __restrict__ skippre) {
    int idx = blockIdx.x * 256 + threadIdx.x;   // 2 * 64 * 512 = 65536
    int mat = idx >> 15;
    int rem = idx & 32767;
    int m = rem >> 9, n = rem & 511;
    const float* p = spart + ((size_t)(mat * SIG_KC) * 64 + m) * UU + n;
    float v = 0.f;
#pragma unroll 2
    for (int kc = 0; kc < SIG_KC; ++kc) v += p[(size_t)kc * 64 * UU];
    if (mat == 0) {
        v += b1[n];
        h1b[(size_t)m * UU + n] = f2bf(v > 0.f ? v : expf(v) - 1.0f);
    } else {
        skippre[(size_t)m * UU + n] = v;
    }
}

// ---------------------------------------------------------------------------
// K6: direct h2 = h1b @ W2t^T + b2 -> bf16
// ---------------------------------------------------------------------------
__global__ __launch_bounds__(64) void k_h2_direct(const unsigned short* __restrict__ h1b,
                                                  const unsigned short* __restrict__ W2t,
                                                  const float* __restrict__ b2,
                                                  unsigned short* __restrict__ h2b) {
    int lane = threadIdx.x;
    int mt = blockIdx.x, nt = blockIdx.y;
    const unsigned short* pa = h1b + (size_t)(mt * 16 + (lane & 15)) * 512 + (lane >> 4) * 8;
    const unsigned short* pb = W2t + (size_t)(nt * 16 + (lane & 15)) * 512 + (lane >> 4) * 8;
    f32x4 acc0 = (f32x4)(0.f), acc1 = (f32x4)(0.f);
#pragma unroll
    for (int t = 0; t < 16; t += 2) {
        bf16x8 a0 = *(const bf16x8*)(pa + t * 32);
        bf16x8 b0 = *(const bf16x8*)(pb + t * 32);
        bf16x8 a1 = *(const bf16x8*)(pa + t * 32 + 32);
        bf16x8 b1v = *(const bf16x8*)(pb + t * 32 + 32);
        acc0 = __builtin_amdgcn_mfma_f32_16x16x32_bf16(a0, b0, acc0, 0, 0, 0);
        acc1 = __builtin_amdgcn_mfma_f32_16x16x32_bf16(a1, b1v, acc1, 0, 0, 0);
    }
    int col = lane & 15, quad = lane >> 4;
    int j = nt * 16 + col;
    float bb = b2[j];
#pragma unroll
    for (int reg = 0; reg < 4; ++reg) {
        int row = mt * 16 + quad * 4 + reg;
        h2b[(size_t)row * UU + j] = f2bf(acc0[reg] + acc1[reg] + bb);
    }
}

// ---------------------------------------------------------------------------
// K7: direct GLU
// ---------------------------------------------------------------------------
__global__ __launch_bounds__(64) void k_glu_direct(const unsigned short* __restrict__ h2b,
                                                   const unsigned short* __restrict__ W3t,
                                                   const unsigned short* __restrict__ W4t,
                                                   const float* __restrict__ b3,
                                                   const float* __restrict__ b4,
                                                   const float* __restrict__ skippre,
                                                   const float* __restrict__ skb,
                                                   float* __restrict__ yv) {
    int lane = threadIdx.x;
    int mt = blockIdx.x, nt = blockIdx.y;
    const unsigned short* pa = h2b + (size_t)(mt * 16 + (lane & 15)) * 512 + (lane >> 4) * 8;
    const unsigned short* pb3 = W3t + (size_t)(nt * 16 + (lane & 15)) * 512 + (lane >> 4) * 8;
    const unsigned short* pb4 = W4t + (size_t)(nt * 16 + (lane & 15)) * 512 + (lane >> 4) * 8;
    f32x4 acc3 = (f32x4)(0.f), acc4 = (f32x4)(0.f);
#pragma unroll
    for (int t = 0; t < 16; ++t) {
        bf16x8 a = *(const bf16x8*)(pa + t * 32);
        bf16x8 b3f = *(const bf16x8*)(pb3 + t * 32);
        bf16x8 b4f = *(const bf16x8*)(pb4 + t * 32);
        acc3 = __builtin_amdgcn_mfma_f32_16x16x32_bf16(a, b3f, acc3, 0, 0, 0);
        acc4 = __builtin_amdgcn_mfma_f32_16x16x32_bf16(a, b4f, acc4, 0, 0, 0);
    }
    int col = lane & 15, quad = lane >> 4;
    int j = nt * 16 + col;
    float bb3 = b3[j], bb4 = b4[j], sb = skb[j];
#pragma unroll
    for (int reg = 0; reg < 4; ++reg) {
        int row = mt * 16 + quad * 4 + reg;
        float g = sigmoidf(acc3[reg] + bb3);
        yv[(size_t)row * UU + j] = skippre[(size_t)row * UU + j] + sb + g * (acc4[reg] + bb4);
    }
}

// ---------------------------------------------------------------------------
// K8: layernorm + softmax -> attn
// ---------------------------------------------------------------------------
__device__ __forceinline__ float block_sum(float v, float* red) {
    int tid = threadIdx.x;
#pragma unroll
    for (int off = 32; off > 0; off >>= 1) v += __shfl_down(v, off);
    __syncthreads();
    if ((tid & 63) == 0) red[tid >> 6] = v;
    __syncthreads();
    float r = red[0];
#pragma unroll
    for (int i = 1; i < 8; ++i) r += red[i];
    return r;
}
__device__ __forceinline__ float block_max(float v, float* red) {
    int tid = threadIdx.x;
#pragma unroll
    for (int off = 32; off > 0; off >>= 1) v = fmaxf(v, __shfl_down(v, off));
    __syncthreads();
    if ((tid & 63) == 0) red[tid >> 6] = v;
    __syncthreads();
    float r = red[0];
#pragma unroll
    for (int i = 1; i < 8; ++i) r = fmaxf(r, red[i]);
    return r;
}

__global__ void k_lnsm(const float* __restrict__ yv, const float* __restrict__ gamma,
                       const float* __restrict__ beta, float* __restrict__ attn) {
    int b = blockIdx.x, u = threadIdx.x;
    __shared__ float red[8];
    float v = yv[(size_t)b * UU + u];
    float mu = block_sum(v, red) * (1.0f / UU);
    float d = v - mu;
    float var = block_sum(d * d, red) * (1.0f / UU);
    float z = d * rsqrtf(var + 1e-3f) * gamma[u] + beta[u];
    float m = block_max(z, red);
    float e = expf(z - m);
    float Z = block_sum(e, red);
    attn[(size_t)b * UU + u] = e / Z;
}

// ---------------------------------------------------------------------------
// K9: attn-weighted KAN-feature reduction, lane-parallel over s.
// ---------------------------------------------------------------------------
__global__ __launch_bounds__(256) void k_kan_red(const unsigned short* __restrict__ wT,
                                                 const float* __restrict__ attn,
                                                 unsigned short* __restrict__ Aredb) {
    int b = blockIdx.x;
    int lane = threadIdx.x & 63;
    int f = blockIdx.y * 4 + (threadIdx.x >> 6);

    const u16x8 wv = *(const u16x8*)(wT + ((size_t)b * FF + f) * SS + lane * 8);
    const float* ap = attn + (size_t)b * UU + lane * 8;
    float4 a0 = *(const float4*)ap;
    float4 a1 = *(const float4*)(ap + 4);

    float acc[9] = {};
#pragma unroll
    for (int s = 0; s < 8; ++s) {
        float w = __uint_as_float((unsigned int)wv[s] << 16);
        float a = (s < 4) ? ((s == 0) ? a0.x : (s == 1) ? a0.y : (s == 2) ? a0.z : a0.w)
                          : ((s == 4) ? a1.x : (s == 5) ? a1.y : (s == 6) ? a1.z : a1.w);
        float t = (w + 2.2f) * 2.5f;
        float cf = floorf(fminf(fmaxf(t, -2.f), 13.f));
        int c = (int)cf;
        float u = t - cf;
        float u2 = u * u, u3 = u2 * u;
        float p0 = u3 * (1.f / 6.f);
        float p1 = (-3.f * u3 + 3.f * u2 + 3.f * u + 1.f) * (1.f / 6.f);
        float p2 = (3.f * u3 - 6.f * u2 + 4.f) * (1.f / 6.f);
        float onemu = 1.f - u;
        float p3 = onemu * onemu * onemu * (1.f / 6.f);
#pragma unroll
        for (int k2 = 0; k2 < 8; ++k2) {
            int d = c - k2;
            float v = (d == 0) ? p0 : (d == 1) ? p1 : (d == 2) ? p2 : (d == 3) ? p3 : 0.f;
            acc[k2] += a * v;
        }
        acc[8] += a * (w * sigmoidf(w));
    }

#pragma unroll
    for (int off = 1; off < 64; off <<= 1) {
#pragma unroll
        for (int k = 0; k < 9; ++k) acc[k] += __shfl_xor(acc[k], off);
    }

    if (lane == 0) {
        const float sc = 1.0f / SS;
        u16x8 ov;
#pragma unroll
        for (int k = 0; k < 8; ++k) ov[k] = f2bf(acc[k] * sc);
        *(u16x8*)(Aredb + (size_t)b * KK + f * 8) = ov;
        Aredb[(size_t)b * KK + 1024 + f] = f2bf(acc[8] * sc);
    }
}

// ---------------------------------------------------------------------------
// K10: direct current = Aredb @ Wt^T -> bf16 into comb_b left half
// ---------------------------------------------------------------------------
__global__ __launch_bounds__(64) void k_cur_direct(const unsigned short* __restrict__ Aredb,
                                                   const unsigned short* __restrict__ Wt,
                                                   unsigned short* __restrict__ comb_b) {
    int lane = threadIdx.x;
    int mt = blockIdx.x, nt = blockIdx.y;
    const unsigned short* pa = Aredb + (size_t)(mt * 16 + (lane & 15)) * KK + (lane >> 4) * 8;
    const unsigned short* pb = Wt + (size_t)(nt * 16 + (lane & 15)) * KK + (lane >> 4) * 8;
    f32x4 acc0 = (f32x4)(0.f), acc1 = (f32x4)(0.f);
#pragma unroll 6
    for (int t = 0; t < KK / 32; t += 2) {
        bf16x8 a0 = *(const bf16x8*)(pa + t * 32);
        bf16x8 b0 = *(const bf16x8*)(pb + t * 32);
        bf16x8 a1 = *(const bf16x8*)(pa + t * 32 + 32);
        bf16x8 b1v = *(const bf16x8*)(pb + t * 32 + 32);
        acc0 = __builtin_amdgcn_mfma_f32_16x16x32_bf16(a0, b0, acc0, 0, 0, 0);
        acc1 = __builtin_amdgcn_mfma_f32_16x16x32_bf16(a1, b1v, acc1, 0, 0, 0);
    }
    int col = lane & 15, quad = lane >> 4;
    int j = nt * 16 + col;
#pragma unroll
    for (int reg = 0; reg < 4; ++reg) {
        int row = mt * 16 + quad * 4 + reg;
        comb_b[(size_t)row * 1024 + j] = f2bf(acc0[reg] + acc1[reg]);
    }
}

// ---------------------------------------------------------------------------
// K11 (fused): all 4 gate GEMMs + LSTM cell update.  grid (4,32) x 64.
// ---------------------------------------------------------------------------
__global__ __launch_bounds__(64) void k_gates_cell(const unsigned short* __restrict__ comb_b,
                                                   const unsigned short* __restrict__ Wgt,
                                                   const float* __restrict__ bf_,
                                                   const float* __restrict__ bi_,
                                                   const float* __restrict__ bc_,
                                                   const float* __restrict__ bo_,
                                                   const float* __restrict__ c_prev,
                                                   float* __restrict__ out) {
    int lane = threadIdx.x;
    int mt = blockIdx.x, jt = blockIdx.y;
    const unsigned short* pa = comb_b + (size_t)(mt * 16 + (lane & 15)) * 1024 + (lane >> 4) * 8;
    const unsigned short* pb0 = Wgt + (size_t)(0 * 512 + jt * 16 + (lane & 15)) * 1024 + (lane >> 4) * 8;
    const unsigned short* pb1 = Wgt + (size_t)(1 * 512 + jt * 16 + (lane & 15)) * 1024 + (lane >> 4) * 8;
    const unsigned short* pb2 = Wgt + (size_t)(2 * 512 + jt * 16 + (lane & 15)) * 1024 + (lane >> 4) * 8;
    const unsigned short* pb3 = Wgt + (size_t)(3 * 512 + jt * 16 + (lane & 15)) * 1024 + (lane >> 4) * 8;
    f32x4 accf = (f32x4)(0.f), acci = (f32x4)(0.f), accc = (f32x4)(0.f), acco = (f32x4)(0.f);
#pragma unroll 4
    for (int t = 0; t < 32; ++t) {
        bf16x8 a = *(const bf16x8*)(pa + t * 32);
        bf16x8 b0 = *(const bf16x8*)(pb0 + t * 32);
        bf16x8 b1 = *(const bf16x8*)(pb1 + t * 32);
        bf16x8 b2 = *(const bf16x8*)(pb2 + t * 32);
        bf16x8 b3 = *(const bf16x8*)(pb3 + t * 32);
        accf = __builtin_amdgcn_mfma_f32_16x16x32_bf16(a, b0, accf, 0, 0, 0);
        acci = __builtin_amdgcn_mfma_f32_16x16x32_bf16(a, b1, acci, 0, 0, 0);
        accc = __builtin_amdgcn_mfma_f32_16x16x32_bf16(a, b2, accc, 0, 0, 0);
        acco = __builtin_amdgcn_mfma_f32_16x16x32_bf16(a, b3, acco, 0, 0, 0);
    }
    int col = lane & 15, quad = lane >> 4;
    int j = jt * 16 + col;
    float bfv = bf_[j], biv = bi_[j], bcv = bc_[j], bov = bo_[j];
#pragma unroll
    for (int reg = 0; reg < 4; ++reg) {
        int row = mt * 16 + quad * 4 + reg;
        float f = sigmoidf(accf[reg] + bfv);
        float ii = sigmoidf(acci[reg] + biv);
        float cd = tanhf(accc[reg] + bcv);
        float o = sigmoidf(acco[reg] + bov);
        float cn = f * c_prev[(size_t)row * UU + j] + ii * cd;
        out[(size_t)row * UU + j] = o * tanhf(cn);
        out[(size_t)BB * UU + (size_t)row * UU + j] = cn;
    }
}

// ---------------------------------------------------------------------------
extern "C" void kernel_launch(void* const* d_in, const int* in_sizes, int n_in,
                              void* d_out, int out_size, void* d_ws, size_t ws_size,
                              hipStream_t stream) {
    const float* inp   = (const float*)d_in[0];
    const float* hprev = (const float*)d_in[1];
    const float* cprev = (const float*)d_in[2];
    const float* tk    = (const float*)d_in[3];
    const float* basew = (const float*)d_in[4];
    const float* splw  = (const float*)d_in[5];
    const float* gw1   = (const float*)d_in[6];
    const float* gb1   = (const float*)d_in[7];
    const float* gw2   = (const float*)d_in[8];
    const float* gb2   = (const float*)d_in[9];
    const float* gw3   = (const float*)d_in[10];
    const float* gb3   = (const float*)d_in[11];
    const float* gw4   = (const float*)d_in[12];
    const float* gb4   = (const float*)d_in[13];
    const float* gsw   = (const float*)d_in[14];
    const float* gsb   = (const float*)d_in[15];
    const float* lng   = (const float*)d_in[16];
    const float* lnb   = (const float*)d_in[17];
    const float* wf    = (const float*)d_in[18];
    const float* bf_   = (const float*)d_in[19];
    const float* wi    = (const float*)d_in[20];
    const float* bi_   = (const float*)d_in[21];
    const float* wc    = (const float*)d_in[22];
    const float* bc_   = (const float*)d_in[23];
    const float* wo    = (const float*)d_in[24];
    const float* bo_   = (const float*)d_in[25];
    float* out = (float*)d_out;

    float* ws = (float*)d_ws;
    size_t o = 0;
    unsigned short* Wt  = (unsigned short*)(ws + o); o += (size_t)UU * KK / 2;
    unsigned short* aT = (unsigned short*)(ws + o); o += (size_t)BB * FF * SS / 2;  // 8.4 MB
    unsigned short* dT = (unsigned short*)(ws + o); o += (size_t)BB * FF * SS / 2;  // 8.4 MB
    unsigned short* wT = (unsigned short*)(ws + o); o += (size_t)BB * FF * SS / 2;  // 8.4 MB
    unsigned short* sigb = (unsigned short*)(ws + o); o += (size_t)BB * K3 / 2;
    float* spart    = ws + o; o += (size_t)2 * SIG_KC * 64 * UU;                 // 22.5 MB
    float* skippre  = ws + o; o += (size_t)BB * UU;
    unsigned short* h1b = (unsigned short*)(ws + o); o += (size_t)BB * UU / 2;
    unsigned short* h2b = (unsigned short*)(ws + o); o += (size_t)BB * UU / 2;
    float* yv       = ws + o; o += (size_t)BB * UU;
    float* attn     = ws + o; o += (size_t)BB * UU;
    unsigned short* Aredb = (unsigned short*)(ws + o); o += (size_t)BB * KK / 2;
    unsigned short* W2t = (unsigned short*)(ws + o); o += (size_t)512 * 512 / 2;
    unsigned short* W3t = (unsigned short*)(ws + o); o += (size_t)512 * 512 / 2;
    unsigned short* W4t = (unsigned short*)(ws + o); o += (size_t)512 * 512 / 2;
    unsigned short* Wgt = (unsigned short*)(ws + o); o += (size_t)2048 * 1024 / 2;
    unsigned short* comb_b = (unsigned short*)(ws + o); o += (size_t)BB * 1024 / 2;
    (void)ws_size; (void)in_sizes; (void)n_in; (void)out_size;

    k_prep<<<dim3(16, 8, 8), 256, 0, stream>>>(splw, basew, hprev, gw2, gw3, gw4, wf, wi, wc, wo,
                                               Wt, comb_b, W2t, W3t, W4t, Wgt);
    k_adprep<<<dim3(8, 2, BB), 256, 0, stream>>>(inp, tk, aT, dT, wT);
    k_sig_quad<<<dim3(4, BB), 256, 0, stream>>>(aT, dT, inp, tk, sigb);
    k_sig_fused<<<dim3(8, SIG_KC, 2), 256, 0, stream>>>(sigb, gw1, gsw, spart);
    k_sig_red2<<<256, 256, 0, stream>>>(spart, gb1, h1b, skippre);
    k_h2_direct<<<dim3(4, 32), 64, 0, stream>>>(h1b, W2t, gb2, h2b);
    k_glu_direct<<<dim3(4, 32), 64, 0, stream>>>(h2b, W3t, W4t, gb3, gb4, skippre, gsb, yv);
    k_lnsm<<<BB, UU, 0, stream>>>(yv, lng, lnb, attn);
    k_kan_red<<<dim3(BB, FF / 4), 256, 0, stream>>>(wT, attn, Aredb);
    k_cur_direct<<<dim3(4, 32), 64, 0, stream>>>(Aredb, Wt, comb_b);
    k_gates_cell<<<dim3(4, 32), 64, 0, stream>>>(comb_b, Wgt, bf_, bi_, bc_, bo_, cprev, out);
}

// Round 10
// 247.956 us; speedup vs baseline: 1.0483x; 1.0483x over previous
//
#include <hip/hip_runtime.h>
#include <math.h>

#define BB 64
#define SS 512
#define FF 128
#define UU 512
#define SIGDIM (FF + FF*FF)   // 16512
#define K3 16512              // sig GEMM K
#define KK 1152               // KAN GEMM K: 1024 spline + 128 base
#define SIG_KC 43             // K-chunks for fused sig GEMM (43*6*64 = 16512)
#define SIG_STEPS 6

typedef __attribute__((ext_vector_type(8))) __bf16 bf16x8;
typedef __attribute__((ext_vector_type(8))) unsigned short u16x8;
typedef __attribute__((ext_vector_type(4))) float f32x4;

__device__ __forceinline__ unsigned short f2bf(float x) {
    unsigned int u = __float_as_uint(x);
    unsigned int r = u + 0x7FFFu + ((u >> 16) & 1u);   // RNE
    return (unsigned short)(r >> 16);
}

__device__ __forceinline__ float sigmoidf(float x) { return 1.0f / (1.0f + expf(-x)); }

// ---------------------------------------------------------------------------
// K1 (merged prep): z=0 -> Wt bf16 [512 u][1152 k] + h_prev -> comb_b right
// half; z=1..7 -> small-weight transposes.  grid (16,8,8) x 256 -- wide.
// ---------------------------------------------------------------------------
__global__ __launch_bounds__(256) void k_prep(const float* __restrict__ splw,
                                              const float* __restrict__ basew,
                                              const float* __restrict__ h_prev,
                                              const float* __restrict__ w2, const float* __restrict__ w3,
                                              const float* __restrict__ w4, const float* __restrict__ wf,
                                              const float* __restrict__ wi, const float* __restrict__ wc,
                                              const float* __restrict__ wo,
                                              unsigned short* __restrict__ Wt,
                                              unsigned short* __restrict__ comb_b,
                                              unsigned short* __restrict__ W2t,
                                              unsigned short* __restrict__ W3t,
                                              unsigned short* __restrict__ W4t,
                                              unsigned short* __restrict__ Wgt) {
    int z = blockIdx.z;
    int tid = threadIdx.x;
    if (z == 0) {
        int base = (blockIdx.y * 16 + blockIdx.x) * 256 + tid;   // [0, 32768)
        {
            int b = base >> 9, uu = base & 511;
            comb_b[(size_t)b * 1024 + 512 + uu] = f2bf(h_prev[base]);
        }
        for (int idx = base; idx < UU * KK; idx += 128 * 256) {
            int u = idx / KK, c = idx % KK;
            float v = (c < 1024) ? splw[(size_t)u * 1024 + c] : basew[(size_t)(c - 1024) * UU + u];
            Wt[idx] = f2bf(v);
        }
        return;
    }
    int zz = z - 1;
    int Kdim = (zz < 3) ? 512 : 1024;
    int kt = blockIdx.x, ut = blockIdx.y;
    if (kt * 64 >= Kdim) return;
    const float* src;
    unsigned short* dst;
    switch (zz) {
        case 0: src = w2; dst = W2t; break;
        case 1: src = w3; dst = W3t; break;
        case 2: src = w4; dst = W4t; break;
        case 3: src = wf; dst = Wgt; break;
        case 4: src = wi; dst = Wgt + (size_t)512 * 1024; break;
        case 5: src = wc; dst = Wgt + (size_t)1024 * 1024; break;
        default: src = wo; dst = Wgt + (size_t)1536 * 1024; break;
    }
    __shared__ float tile[64][67];
    int k0 = kt * 64, u0 = ut * 64;
#pragma unroll
    for (int p = 0; p < 4; ++p) {
        int e = p * 256 + tid;
        int kk = e >> 4, c4 = (e & 15) * 4;
        const float4 v = *(const float4*)(src + (size_t)(k0 + kk) * UU + u0 + c4);
        tile[kk][c4 + 0] = v.x;
        tile[kk][c4 + 1] = v.y;
        tile[kk][c4 + 2] = v.z;
        tile[kk][c4 + 3] = v.w;
    }
    __syncthreads();
    int kk0 = (tid & 7) * 8;
#pragma unroll
    for (int p = 0; p < 2; ++p) {
        int uu = (tid >> 3) + p * 32;
        u16x8 ov;
#pragma unroll
        for (int j = 0; j < 8; ++j) ov[j] = f2bf(tile[kk0 + j][uu]);
        *(u16x8*)(dst + (size_t)(u0 + uu) * Kdim + k0 + kk0) = ov;
    }
}

// ---------------------------------------------------------------------------
// K2: a/d/w prep, single fp32 LDS tile.
// ---------------------------------------------------------------------------
__global__ __launch_bounds__(256) void k_adprep(const float* __restrict__ inp,
                                                const float* __restrict__ tk,
                                                unsigned short* __restrict__ aT,
                                                unsigned short* __restrict__ dT,
                                                unsigned short* __restrict__ wT) {
    int tt0 = blockIdx.x * 64, f0 = blockIdx.y * 64, b = blockIdx.z;
    __shared__ float wS[65][67];
    __shared__ float w0S[64];
    int tid = threadIdx.x;
    const float* ib = inp + (size_t)b * SS * FF;
    if (tid < 64) w0S[tid] = tk[0] * ib[f0 + tid];
#pragma unroll
    for (int p = 0; p < 5; ++p) {
        int e = p * 256 + tid;
        if (e < 65 * 16) {
            int row = e >> 4, c4 = (e & 15) * 4;
            int t = tt0 + row;
            if (t < SS) {
                float tkt = tk[t];
                const float4 v = *(const float4*)(ib + (size_t)t * FF + f0 + c4);
                wS[row][c4 + 0] = tkt * v.x;
                wS[row][c4 + 1] = tkt * v.y;
                wS[row][c4 + 2] = tkt * v.z;
                wS[row][c4 + 3] = tkt * v.w;
            } else {
                wS[row][c4 + 0] = 0.f;
                wS[row][c4 + 1] = 0.f;
                wS[row][c4 + 2] = 0.f;
                wS[row][c4 + 3] = 0.f;
            }
        }
    }
    __syncthreads();
    int t8 = (tid & 7) * 8;
#pragma unroll
    for (int p = 0; p < 2; ++p) {
        int ff = (tid >> 3) + p * 32;
        float w0 = w0S[ff];
        u16x8 av, dv, wv;
#pragma unroll
        for (int j = 0; j < 8; ++j) {
            int tt = t8 + j;
            float w = wS[tt][ff];
            float wn = wS[tt + 1][ff];
            bool valid = (tt0 + tt) < (SS - 1);
            float a = valid ? 0.5f * (w + wn) - w0 : 0.f;
            float d = valid ? wn - w : 0.f;
            av[j] = f2bf(a);
            dv[j] = f2bf(d);
            wv[j] = f2bf(w);
        }
        size_t o = ((size_t)b * FF + f0 + ff) * SS + tt0 + t8;
        *(u16x8*)(aT + o) = av;
        *(u16x8*)(dT + o) = dv;
        *(u16x8*)(wT + o) = wv;
    }
}

// ---------------------------------------------------------------------------
// K3: quadrant-tiled full-K signature GEMM, LDS-staged, writes sigb bf16
// directly.  grid (4 quadrant, 64 b) x 256.
// ---------------------------------------------------------------------------
__global__ __launch_bounds__(256) void k_sig_quad(const unsigned short* __restrict__ aT,
                                                  const unsigned short* __restrict__ dT,
                                                  const float* __restrict__ inp,
                                                  const float* __restrict__ tk,
                                                  unsigned short* __restrict__ sigb) {
    int q = blockIdx.x, b = blockIdx.y;
    int qr = q & 1, qc = q >> 1;
    __shared__ unsigned short aS[64][72];
    __shared__ unsigned short dS[64][72];
    int tid = threadIdx.x, lane = tid & 63;
    int wv = __builtin_amdgcn_readfirstlane(tid >> 6);
    int rowoff = (wv & 1) * 32, coloff = (wv >> 1) * 32;
    const unsigned short* pabase = aT + ((size_t)b * FF + qr * 64) * SS;
    const unsigned short* pdbase = dT + ((size_t)b * FF + qc * 64) * SS;

    f32x4 acc[2][2];
#pragma unroll
    for (int i = 0; i < 2; ++i)
#pragma unroll
        for (int j = 0; j < 2; ++j) acc[i][j] = (f32x4)(0.f);

    int arow0 = rowoff + (lane & 15);
    int drow0 = coloff + (lane & 15);
    int kq = (lane >> 4) * 8;

    for (int kc = 0; kc < 8; ++kc) {
#pragma unroll
        for (int p = 0; p < 2; ++p) {
            int e = p * 256 + tid;          // 512 = 64 rows x 8 groups of 8 hw
            int row = e >> 3, k8 = (e & 7) * 8;
            *(u16x8*)&aS[row][k8] = *(const u16x8*)(pabase + (size_t)row * SS + kc * 64 + k8);
            *(u16x8*)&dS[row][k8] = *(const u16x8*)(pdbase + (size_t)row * SS + kc * 64 + k8);
        }
        __syncthreads();
#pragma unroll
        for (int ks = 0; ks < 2; ++ks) {
            bf16x8 af0 = *(const bf16x8*)&aS[arow0][ks * 32 + kq];
            bf16x8 af1 = *(const bf16x8*)&aS[arow0 + 16][ks * 32 + kq];
            bf16x8 df0 = *(const bf16x8*)&dS[drow0][ks * 32 + kq];
            bf16x8 df1 = *(const bf16x8*)&dS[drow0 + 16][ks * 32 + kq];
            acc[0][0] = __builtin_amdgcn_mfma_f32_16x16x32_bf16(af0, df0, acc[0][0], 0, 0, 0);
            acc[0][1] = __builtin_amdgcn_mfma_f32_16x16x32_bf16(af0, df1, acc[0][1], 0, 0, 0);
            acc[1][0] = __builtin_amdgcn_mfma_f32_16x16x32_bf16(af1, df0, acc[1][0], 0, 0, 0);
            acc[1][1] = __builtin_amdgcn_mfma_f32_16x16x32_bf16(af1, df1, acc[1][1], 0, 0, 0);
        }
        __syncthreads();
    }

    unsigned short* ob = sigb + (size_t)b * SIGDIM;
    if (q == 0 && tid < FF) {
        float v = tk[SS - 1] * inp[((size_t)b * SS + SS - 1) * FF + tid] - tk[0] * inp[(size_t)b * SS * FF + tid];
        ob[tid] = f2bf(v);
    }
    int quad = lane >> 4, col = lane & 15;
#pragma unroll
    for (int rt = 0; rt < 2; ++rt)
#pragma unroll
        for (int ct = 0; ct < 2; ++ct)
#pragma unroll
            for (int reg = 0; reg < 4; ++reg)
                ob[FF + (qr * 64 + rowoff + rt * 16 + quad * 4 + reg) * FF
                      + qc * 64 + coloff + ct * 16 + col] = f2bf(acc[rt][ct][reg]);
}

// ---------------------------------------------------------------------------
// K4: fused sig GEMM vs untransposed fp32 weights.
// grid (8 nt, 43 kc, 2 mat) x 256.
// ---------------------------------------------------------------------------
__global__ __launch_bounds__(256) void k_sig_fused(const unsigned short* __restrict__ sigb,
                                                   const float* __restrict__ w1,
                                                   const float* __restrict__ gsw,
                                                   float* __restrict__ spart) {
    int nt = blockIdx.x, kc = blockIdx.y, mat = blockIdx.z;
    const float* src = mat ? gsw : w1;
    __shared__ float tile[64][67];
    int tid = threadIdx.x, lane = tid & 63;
    int wv = __builtin_amdgcn_readfirstlane(tid >> 6);
    int u0 = nt * 64;
    int n0 = wv * 16;
    int kbase = kc * (SIG_STEPS * 64);

    f32x4 acc[4];
#pragma unroll
    for (int i = 0; i < 4; ++i) acc[i] = (f32x4)(0.f);

    int nn = lane & 15;
    int kq = (lane >> 4) * 8;
    const unsigned short* pab = sigb + (size_t)nn * K3 + kq;

    for (int step = 0; step < SIG_STEPS; ++step) {
        int k0 = kbase + step * 64;
#pragma unroll
        for (int p = 0; p < 4; ++p) {
            int e = p * 256 + tid;
            int kk = e >> 4, c4 = (e & 15) * 4;
            const float4 v = *(const float4*)(src + (size_t)(k0 + kk) * UU + u0 + c4);
            tile[kk][c4 + 0] = v.x;
            tile[kk][c4 + 1] = v.y;
            tile[kk][c4 + 2] = v.z;
            tile[kk][c4 + 3] = v.w;
        }
        __syncthreads();
#pragma unroll
        for (int s = 0; s < 2; ++s) {
            u16x8 ub;
            int kb = s * 32 + kq;
#pragma unroll
            for (int j = 0; j < 8; ++j) ub[j] = f2bf(tile[kb + j][n0 + nn]);
            bf16x8 bfrag = __builtin_bit_cast(bf16x8, ub);
#pragma unroll
            for (int rt = 0; rt < 4; ++rt) {
                bf16x8 afrag = *(const bf16x8*)(pab + (size_t)(rt * 16) * K3 + k0 + s * 32);
                acc[rt] = __builtin_amdgcn_mfma_f32_16x16x32_bf16(afrag, bfrag, acc[rt], 0, 0, 0);
            }
        }
        __syncthreads();
    }

    int col = lane & 15, quad = lane >> 4;
    float* P = spart + ((size_t)(mat * SIG_KC + kc) * 64) * UU;
#pragma unroll
    for (int rt = 0; rt < 4; ++rt)
#pragma unroll
        for (int reg = 0; reg < 4; ++reg)
            P[(size_t)(rt * 16 + quad * 4 + reg) * UU + u0 + n0 + col] = acc[rt][reg];
}

// ---------------------------------------------------------------------------
// K5: reduce 43 K-chunk partials.
// ---------------------------------------------------------------------------
__global__ __launch_bounds__(256) void k_sig_red2(const float* __restrict__ spart,
                                                  const float* __restrict__ b1,
                                                  unsigned short* __restrict__ h1b,
                                                  float* __restrict__ skippre) {
    int idx = blockIdx.x * 256 + threadIdx.x;   // 2 * 64 * 512 = 65536
    int mat = idx >> 15;
    int rem = idx & 32767;
    int m = rem >> 9, n = rem & 511;
    const float* p = spart + ((size_t)(mat * SIG_KC) * 64 + m) * UU + n;
    float v = 0.f;
#pragma unroll
    for (int kc = 0; kc < SIG_KC; ++kc) v += p[(size_t)kc * 64 * UU];
    if (mat == 0) {
        v += b1[n];
        h1b[(size_t)m * UU + n] = f2bf(v > 0.f ? v : expf(v) - 1.0f);
    } else {
        skippre[(size_t)m * UU + n] = v;
    }
}

// ---------------------------------------------------------------------------
// K6: direct h2 = h1b @ W2t^T + b2 -> bf16
// ---------------------------------------------------------------------------
__global__ __launch_bounds__(64) void k_h2_direct(const unsigned short* __restrict__ h1b,
                                                  const unsigned short* __restrict__ W2t,
                                                  const float* __restrict__ b2,
                                                  unsigned short* __restrict__ h2b) {
    int lane = threadIdx.x;
    int mt = blockIdx.x, nt = blockIdx.y;
    const unsigned short* pa = h1b + (size_t)(mt * 16 + (lane & 15)) * 512 + (lane >> 4) * 8;
    const unsigned short* pb = W2t + (size_t)(nt * 16 + (lane & 15)) * 512 + (lane >> 4) * 8;
    f32x4 acc0 = (f32x4)(0.f), acc1 = (f32x4)(0.f);
#pragma unroll
    for (int t = 0; t < 16; t += 2) {
        bf16x8 a0 = *(const bf16x8*)(pa + t * 32);
        bf16x8 b0 = *(const bf16x8*)(pb + t * 32);
        bf16x8 a1 = *(const bf16x8*)(pa + t * 32 + 32);
        bf16x8 b1v = *(const bf16x8*)(pb + t * 32 + 32);
        acc0 = __builtin_amdgcn_mfma_f32_16x16x32_bf16(a0, b0, acc0, 0, 0, 0);
        acc1 = __builtin_amdgcn_mfma_f32_16x16x32_bf16(a1, b1v, acc1, 0, 0, 0);
    }
    int col = lane & 15, quad = lane >> 4;
    int j = nt * 16 + col;
    float bb = b2[j];
#pragma unroll
    for (int reg = 0; reg < 4; ++reg) {
        int row = mt * 16 + quad * 4 + reg;
        h2b[(size_t)row * UU + j] = f2bf(acc0[reg] + acc1[reg] + bb);
    }
}

// ---------------------------------------------------------------------------
// K7: direct GLU
// ---------------------------------------------------------------------------
__global__ __launch_bounds__(64) void k_glu_direct(const unsigned short* __restrict__ h2b,
                                                   const unsigned short* __restrict__ W3t,
                                                   const unsigned short* __restrict__ W4t,
                                                   const float* __restrict__ b3,
                                                   const float* __restrict__ b4,
                                                   const float* __restrict__ skippre,
                                                   const float* __restrict__ skb,
                                                   float* __restrict__ yv) {
    int lane = threadIdx.x;
    int mt = blockIdx.x, nt = blockIdx.y;
    const unsigned short* pa = h2b + (size_t)(mt * 16 + (lane & 15)) * 512 + (lane >> 4) * 8;
    const unsigned short* pb3 = W3t + (size_t)(nt * 16 + (lane & 15)) * 512 + (lane >> 4) * 8;
    const unsigned short* pb4 = W4t + (size_t)(nt * 16 + (lane & 15)) * 512 + (lane >> 4) * 8;
    f32x4 acc3 = (f32x4)(0.f), acc4 = (f32x4)(0.f);
#pragma unroll
    for (int t = 0; t < 16; ++t) {
        bf16x8 a = *(const bf16x8*)(pa + t * 32);
        bf16x8 b3f = *(const bf16x8*)(pb3 + t * 32);
        bf16x8 b4f = *(const bf16x8*)(pb4 + t * 32);
        acc3 = __builtin_amdgcn_mfma_f32_16x16x32_bf16(a, b3f, acc3, 0, 0, 0);
        acc4 = __builtin_amdgcn_mfma_f32_16x16x32_bf16(a, b4f, acc4, 0, 0, 0);
    }
    int col = lane & 15, quad = lane >> 4;
    int j = nt * 16 + col;
    float bb3 = b3[j], bb4 = b4[j], sb = skb[j];
#pragma unroll
    for (int reg = 0; reg < 4; ++reg) {
        int row = mt * 16 + quad * 4 + reg;
        float g = sigmoidf(acc3[reg] + bb3);
        yv[(size_t)row * UU + j] = skippre[(size_t)row * UU + j] + sb + g * (acc4[reg] + bb4);
    }
}

// ---------------------------------------------------------------------------
// K8: layernorm + softmax -> attn
// ---------------------------------------------------------------------------
__device__ __forceinline__ float block_sum(float v, float* red) {
    int tid = threadIdx.x;
#pragma unroll
    for (int off = 32; off > 0; off >>= 1) v += __shfl_down(v, off);
    __syncthreads();
    if ((tid & 63) == 0) red[tid >> 6] = v;
    __syncthreads();
    float r = red[0];
#pragma unroll
    for (int i = 1; i < 8; ++i) r += red[i];
    return r;
}
__device__ __forceinline__ float block_max(float v, float* red) {
    int tid = threadIdx.x;
#pragma unroll
    for (int off = 32; off > 0; off >>= 1) v = fmaxf(v, __shfl_down(v, off));
    __syncthreads();
    if ((tid & 63) == 0) red[tid >> 6] = v;
    __syncthreads();
    float r = red[0];
#pragma unroll
    for (int i = 1; i < 8; ++i) r = fmaxf(r, red[i]);
    return r;
}

__global__ void k_lnsm(const float* __restrict__ yv, const float* __restrict__ gamma,
                       const float* __restrict__ beta, float* __restrict__ attn) {
    int b = blockIdx.x, u = threadIdx.x;
    __shared__ float red[8];
    float v = yv[(size_t)b * UU + u];
    float mu = block_sum(v, red) * (1.0f / UU);
    float d = v - mu;
    float var = block_sum(d * d, red) * (1.0f / UU);
    float z = d * rsqrtf(var + 1e-3f) * gamma[u] + beta[u];
    float m = block_max(z, red);
    float e = expf(z - m);
    float Z = block_sum(e, red);
    attn[(size_t)b * UU + u] = e / Z;
}

// ---------------------------------------------------------------------------
// K9: attn-weighted KAN-feature reduction, lane-parallel over s.
// ---------------------------------------------------------------------------
__global__ __launch_bounds__(256) void k_kan_red(const unsigned short* __restrict__ wT,
                                                 const float* __restrict__ attn,
                                                 unsigned short* __restrict__ Aredb) {
    int b = blockIdx.x;
    int lane = threadIdx.x & 63;
    int f = blockIdx.y * 4 + (threadIdx.x >> 6);

    const u16x8 wv = *(const u16x8*)(wT + ((size_t)b * FF + f) * SS + lane * 8);
    const float* ap = attn + (size_t)b * UU + lane * 8;
    float4 a0 = *(const float4*)ap;
    float4 a1 = *(const float4*)(ap + 4);

    float acc[9] = {};
#pragma unroll
    for (int s = 0; s < 8; ++s) {
        float w = __uint_as_float((unsigned int)wv[s] << 16);
        float a = (s < 4) ? ((s == 0) ? a0.x : (s == 1) ? a0.y : (s == 2) ? a0.z : a0.w)
                          : ((s == 4) ? a1.x : (s == 5) ? a1.y : (s == 6) ? a1.z : a1.w);
        float t = (w + 2.2f) * 2.5f;
        float cf = floorf(fminf(fmaxf(t, -2.f), 13.f));
        int c = (int)cf;
        float u = t - cf;
        float u2 = u * u, u3 = u2 * u;
        float p0 = u3 * (1.f / 6.f);
        float p1 = (-3.f * u3 + 3.f * u2 + 3.f * u + 1.f) * (1.f / 6.f);
        float p2 = (3.f * u3 - 6.f * u2 + 4.f) * (1.f / 6.f);
        float onemu = 1.f - u;
        float p3 = onemu * onemu * onemu * (1.f / 6.f);
#pragma unroll
        for (int k2 = 0; k2 < 8; ++k2) {
            int d = c - k2;
            float v = (d == 0) ? p0 : (d == 1) ? p1 : (d == 2) ? p2 : (d == 3) ? p3 : 0.f;
            acc[k2] += a * v;
        }
        acc[8] += a * (w * sigmoidf(w));
    }

#pragma unroll
    for (int off = 1; off < 64; off <<= 1) {
#pragma unroll
        for (int k = 0; k < 9; ++k) acc[k] += __shfl_xor(acc[k], off);
    }

    if (lane == 0) {
        const float sc = 1.0f / SS;
        u16x8 ov;
#pragma unroll
        for (int k = 0; k < 8; ++k) ov[k] = f2bf(acc[k] * sc);
        *(u16x8*)(Aredb + (size_t)b * KK + f * 8) = ov;
        Aredb[(size_t)b * KK + 1024 + f] = f2bf(acc[8] * sc);
    }
}

// ---------------------------------------------------------------------------
// K10: direct current = Aredb @ Wt^T -> bf16 into comb_b left half
// ---------------------------------------------------------------------------
__global__ __launch_bounds__(64) void k_cur_direct(const unsigned short* __restrict__ Aredb,
                                                   const unsigned short* __restrict__ Wt,
                                                   unsigned short* __restrict__ comb_b) {
    int lane = threadIdx.x;
    int mt = blockIdx.x, nt = blockIdx.y;
    const unsigned short* pa = Aredb + (size_t)(mt * 16 + (lane & 15)) * KK + (lane >> 4) * 8;
    const unsigned short* pb = Wt + (size_t)(nt * 16 + (lane & 15)) * KK + (lane >> 4) * 8;
    f32x4 acc0 = (f32x4)(0.f), acc1 = (f32x4)(0.f);
#pragma unroll 6
    for (int t = 0; t < KK / 32; t += 2) {
        bf16x8 a0 = *(const bf16x8*)(pa + t * 32);
        bf16x8 b0 = *(const bf16x8*)(pb + t * 32);
        bf16x8 a1 = *(const bf16x8*)(pa + t * 32 + 32);
        bf16x8 b1v = *(const bf16x8*)(pb + t * 32 + 32);
        acc0 = __builtin_amdgcn_mfma_f32_16x16x32_bf16(a0, b0, acc0, 0, 0, 0);
        acc1 = __builtin_amdgcn_mfma_f32_16x16x32_bf16(a1, b1v, acc1, 0, 0, 0);
    }
    int col = lane & 15, quad = lane >> 4;
    int j = nt * 16 + col;
#pragma unroll
    for (int reg = 0; reg < 4; ++reg) {
        int row = mt * 16 + quad * 4 + reg;
        comb_b[(size_t)row * 1024 + j] = f2bf(acc0[reg] + acc1[reg]);
    }
}

// ---------------------------------------------------------------------------
// K11 (fused): all 4 gate GEMMs + LSTM cell update.  grid (4,32) x 64.
// ---------------------------------------------------------------------------
__global__ __launch_bounds__(64) void k_gates_cell(const unsigned short* __restrict__ comb_b,
                                                   const unsigned short* __restrict__ Wgt,
                                                   const float* __restrict__ bf_,
                                                   const float* __restrict__ bi_,
                                                   const float* __restrict__ bc_,
                                                   const float* __restrict__ bo_,
                                                   const float* __restrict__ c_prev,
                                                   float* __restrict__ out) {
    int lane = threadIdx.x;
    int mt = blockIdx.x, jt = blockIdx.y;
    const unsigned short* pa = comb_b + (size_t)(mt * 16 + (lane & 15)) * 1024 + (lane >> 4) * 8;
    const unsigned short* pb0 = Wgt + (size_t)(0 * 512 + jt * 16 + (lane & 15)) * 1024 + (lane >> 4) * 8;
    const unsigned short* pb1 = Wgt + (size_t)(1 * 512 + jt * 16 + (lane & 15)) * 1024 + (lane >> 4) * 8;
    const unsigned short* pb2 = Wgt + (size_t)(2 * 512 + jt * 16 + (lane & 15)) * 1024 + (lane >> 4) * 8;
    const unsigned short* pb3 = Wgt + (size_t)(3 * 512 + jt * 16 + (lane & 15)) * 1024 + (lane >> 4) * 8;
    f32x4 accf = (f32x4)(0.f), acci = (f32x4)(0.f), accc = (f32x4)(0.f), acco = (f32x4)(0.f);
#pragma unroll 4
    for (int t = 0; t < 32; ++t) {
        bf16x8 a = *(const bf16x8*)(pa + t * 32);
        bf16x8 b0 = *(const bf16x8*)(pb0 + t * 32);
        bf16x8 b1 = *(const bf16x8*)(pb1 + t * 32);
        bf16x8 b2 = *(const bf16x8*)(pb2 + t * 32);
        bf16x8 b3 = *(const bf16x8*)(pb3 + t * 32);
        accf = __builtin_amdgcn_mfma_f32_16x16x32_bf16(a, b0, accf, 0, 0, 0);
        acci = __builtin_amdgcn_mfma_f32_16x16x32_bf16(a, b1, acci, 0, 0, 0);
        accc = __builtin_amdgcn_mfma_f32_16x16x32_bf16(a, b2, accc, 0, 0, 0);
        acco = __builtin_amdgcn_mfma_f32_16x16x32_bf16(a, b3, acco, 0, 0, 0);
    }
    int col = lane & 15, quad = lane >> 4;
    int j = jt * 16 + col;
    float bfv = bf_[j], biv = bi_[j], bcv = bc_[j], bov = bo_[j];
#pragma unroll
    for (int reg = 0; reg < 4; ++reg) {
        int row = mt * 16 + quad * 4 + reg;
        float f = sigmoidf(accf[reg] + bfv);
        float ii = sigmoidf(acci[reg] + biv);
        float cd = tanhf(accc[reg] + bcv);
        float o = sigmoidf(acco[reg] + bov);
        float cn = f * c_prev[(size_t)row * UU + j] + ii * cd;
        out[(size_t)row * UU + j] = o * tanhf(cn);
        out[(size_t)BB * UU + (size_t)row * UU + j] = cn;
    }
}

// ---------------------------------------------------------------------------
extern "C" void kernel_launch(void* const* d_in, const int* in_sizes, int n_in,
                              void* d_out, int out_size, void* d_ws, size_t ws_size,
                              hipStream_t stream) {
    const float* inp   = (const float*)d_in[0];
    const float* hprev = (const float*)d_in[1];
    const float* cprev = (const float*)d_in[2];
    const float* tk    = (const float*)d_in[3];
    const float* basew = (const float*)d_in[4];
    const float* splw  = (const float*)d_in[5];
    const float* gw1   = (const float*)d_in[6];
    const float* gb1   = (const float*)d_in[7];
    const float* gw2   = (const float*)d_in[8];
    const float* gb2   = (const float*)d_in[9];
    const float* gw3   = (const float*)d_in[10];
    const float* gb3   = (const float*)d_in[11];
    const float* gw4   = (const float*)d_in[12];
    const float* gb4   = (const float*)d_in[13];
    const float* gsw   = (const float*)d_in[14];
    const float* gsb   = (const float*)d_in[15];
    const float* lng   = (const float*)d_in[16];
    const float* lnb   = (const float*)d_in[17];
    const float* wf    = (const float*)d_in[18];
    const float* bf_   = (const float*)d_in[19];
    const float* wi    = (const float*)d_in[20];
    const float* bi_   = (const float*)d_in[21];
    const float* wc    = (const float*)d_in[22];
    const float* bc_   = (const float*)d_in[23];
    const float* wo    = (const float*)d_in[24];
    const float* bo_   = (const float*)d_in[25];
    float* out = (float*)d_out;

    float* ws = (float*)d_ws;
    size_t o = 0;
    unsigned short* Wt  = (unsigned short*)(ws + o); o += (size_t)UU * KK / 2;
    unsigned short* aT = (unsigned short*)(ws + o); o += (size_t)BB * FF * SS / 2;  // 8.4 MB
    unsigned short* dT = (unsigned short*)(ws + o); o += (size_t)BB * FF * SS / 2;  // 8.4 MB
    unsigned short* wT = (unsigned short*)(ws + o); o += (size_t)BB * FF * SS / 2;  // 8.4 MB
    unsigned short* sigb = (unsigned short*)(ws + o); o += (size_t)BB * K3 / 2;
    float* spart    = ws + o; o += (size_t)2 * SIG_KC * 64 * UU;                 // 11.27 MB
    float* skippre  = ws + o; o += (size_t)BB * UU;
    unsigned short* h1b = (unsigned short*)(ws + o); o += (size_t)BB * UU / 2;
    unsigned short* h2b = (unsigned short*)(ws + o); o += (size_t)BB * UU / 2;
    float* yv       = ws + o; o += (size_t)BB * UU;
    float* attn     = ws + o; o += (size_t)BB * UU;
    unsigned short* Aredb = (unsigned short*)(ws + o); o += (size_t)BB * KK / 2;
    unsigned short* W2t = (unsigned short*)(ws + o); o += (size_t)512 * 512 / 2;
    unsigned short* W3t = (unsigned short*)(ws + o); o += (size_t)512 * 512 / 2;
    unsigned short* W4t = (unsigned short*)(ws + o); o += (size_t)512 * 512 / 2;
    unsigned short* Wgt = (unsigned short*)(ws + o); o += (size_t)2048 * 1024 / 2;
    unsigned short* comb_b = (unsigned short*)(ws + o); o += (size_t)BB * 1024 / 2;
    (void)ws_size; (void)in_sizes; (void)n_in; (void)out_size;

    k_prep<<<dim3(16, 8, 8), 256, 0, stream>>>(splw, basew, hprev, gw2, gw3, gw4, wf, wi, wc, wo,
                                               Wt, comb_b, W2t, W3t, W4t, Wgt);
    k_adprep<<<dim3(8, 2, BB), 256, 0, stream>>>(inp, tk, aT, dT, wT);
    k_sig_quad<<<dim3(4, BB), 256, 0, stream>>>(aT, dT, inp, tk, sigb);
    k_sig_fused<<<dim3(8, SIG_KC, 2), 256, 0, stream>>>(sigb, gw1, gsw, spart);
    k_sig_red2<<<256, 256, 0, stream>>>(spart, gb1, h1b, skippre);
    k_h2_direct<<<dim3(4, 32), 64, 0, stream>>>(h1b, W2t, gb2, h2b);
    k_glu_direct<<<dim3(4, 32), 64, 0, stream>>>(h2b, W3t, W4t, gb3, gb4, skippre, gsb, yv);
    k_lnsm<<<BB, UU, 0, stream>>>(yv, lng, lnb, attn);
    k_kan_red<<<dim3(BB, FF / 4), 256, 0, stream>>>(wT, attn, Aredb);
    k_cur_direct<<<dim3(4, 32), 64, 0, stream>>>(Aredb, Wt, comb_b);
    k_gates_cell<<<dim3(4, 32), 64, 0, stream>>>(comb_b, Wgt, bf_, bi_, bc_, bo_, cprev, out);
}